// Round 1
// baseline (307.492 us; speedup 1.0000x reference)
//
#include <hip/hip_runtime.h>

// BottleneckAttention: LN -> QKV(+bias) -> RoPE(q,k) -> softmax(QK^T/8)V -> O-proj + residual
// B=2 N=2048 D=1024 H=16 hd=64. All GEMMs/attention in bf16 MFMA (16x16x32), fp32 accum.
// Verified layouts (learn_hip m89/m91/m120):
//   C/D: col=lane&15, row=(lane>>4)*4+reg
//   A:   m=lane&15,  k=(lane>>4)*8+j
//   B:   n=lane&15,  k=(lane>>4)*8+j   (i.e. C[m][n] = sum_k A[m][k]*B[n][k])

#define SEQ 2048
#define LN_EPS 1e-5f

using short8 = __attribute__((ext_vector_type(8))) short;
using f32x4  = __attribute__((ext_vector_type(4))) float;

__device__ __forceinline__ unsigned short f2bf(float f) {
  union { float f; unsigned u; } v; v.f = f;
  unsigned r = v.u + 0x7FFFu + ((v.u >> 16) & 1u);  // RNE
  return (unsigned short)(r >> 16);
}

// ---------------- weight fp32 -> bf16 ----------------
__global__ __launch_bounds__(256) void convw_kernel(
    const float* __restrict__ wq, const float* __restrict__ wk,
    const float* __restrict__ wv, const float* __restrict__ wo,
    unsigned short* __restrict__ wqkv, unsigned short* __restrict__ wob) {
  const int gid = blockIdx.x * 256 + threadIdx.x;   // 1M float4 units total
  const int m = gid >> 18, e4 = gid & 262143;
  const float* src = (m == 0) ? wq : (m == 1) ? wk : (m == 2) ? wv : wo;
  const float4 v = ((const float4*)src)[e4];
  ushort4 o; o.x = f2bf(v.x); o.y = f2bf(v.y); o.z = f2bf(v.z); o.w = f2bf(v.w);
  if (m < 3) ((ushort4*)wqkv)[(size_t)m * 262144 + e4] = o;
  else       ((ushort4*)wob)[e4] = o;
}

// ---------------- layernorm -> bf16 ----------------
__global__ __launch_bounds__(256) void ln_kernel(
    const float* __restrict__ x, const float* __restrict__ w,
    const float* __restrict__ b, unsigned short* __restrict__ xn) {
  const int row = blockIdx.x, t = threadIdx.x;
  const float4 v = ((const float4*)(x + (size_t)row * 1024))[t];
  float s  = v.x + v.y + v.z + v.w;
  float s2 = v.x * v.x + v.y * v.y + v.z * v.z + v.w * v.w;
#pragma unroll
  for (int off = 32; off >= 1; off >>= 1) {
    s  += __shfl_xor(s, off);
    s2 += __shfl_xor(s2, off);
  }
  __shared__ float red[8];
  const int lane = t & 63, wave = t >> 6;
  if (lane == 0) { red[wave] = s; red[4 + wave] = s2; }
  __syncthreads();
  s  = red[0] + red[1] + red[2] + red[3];
  s2 = red[4] + red[5] + red[6] + red[7];
  const float mu   = s * (1.0f / 1024.0f);
  const float var  = s2 * (1.0f / 1024.0f) - mu * mu;
  const float rstd = rsqrtf(var + LN_EPS);
  const float4 wv = ((const float4*)w)[t];
  const float4 bv = ((const float4*)b)[t];
  ushort4 o;
  o.x = f2bf((v.x - mu) * rstd * wv.x + bv.x);
  o.y = f2bf((v.y - mu) * rstd * wv.y + bv.y);
  o.z = f2bf((v.z - mu) * rstd * wv.z + bv.z);
  o.w = f2bf((v.w - mu) * rstd * wv.w + bv.w);
  ((ushort4*)xn)[(size_t)row * 256 + t] = o;
}

// ---------------- 128x128 MFMA GEMM, C = A * Bw^T (+epilogue) ----------------
// mode 0: QKV  -> bias + RoPE(q,k), write q,k (B,H,N,hd) and v transposed (B,H,hd,N)
// mode 1: Oproj-> + bo + residual x, fp32 out
__global__ __launch_bounds__(256) void gemm_kernel(
    const unsigned short* __restrict__ A,   // M x 1024 bf16, row-major
    const unsigned short* __restrict__ Bw,  // Ncols x 1024 bf16 (one row per output col)
    int mode,
    const float* __restrict__ bq, const float* __restrict__ bk, const float* __restrict__ bv,
    unsigned short* __restrict__ qb, unsigned short* __restrict__ kb,
    unsigned short* __restrict__ vtb,
    const float* __restrict__ bo, const float* __restrict__ xres, float* __restrict__ out) {
  __shared__ unsigned short lA[128 * 72];
  __shared__ unsigned short lB[128 * 72];
  const int tid = threadIdx.x;
  const int lane = tid & 63, wave = tid >> 6;
  const int lr = lane & 15, quad = lane >> 4;
  const int wm = (wave >> 1) * 64, wn = (wave & 1) * 64;
  const int n0 = blockIdx.x * 128, m0 = blockIdx.y * 128;

  f32x4 acc[4][4];
#pragma unroll
  for (int i = 0; i < 4; ++i)
#pragma unroll
    for (int j = 0; j < 4; ++j) acc[i][j] = (f32x4){0.f, 0.f, 0.f, 0.f};

  for (int kt = 0; kt < 16; ++kt) {
    __syncthreads();
#pragma unroll
    for (int p = 0; p < 4; ++p) {
      int u = tid + p * 256;
      int row = u >> 3, c16 = u & 7;
      *(uint4*)&lA[row * 72 + c16 * 8] =
          *(const uint4*)&A[(size_t)(m0 + row) * 1024 + kt * 64 + c16 * 8];
      *(uint4*)&lB[row * 72 + c16 * 8] =
          *(const uint4*)&Bw[(size_t)(n0 + row) * 1024 + kt * 64 + c16 * 8];
    }
    __syncthreads();
#pragma unroll
    for (int kk = 0; kk < 2; ++kk) {
      short8 a[4], b[4];
#pragma unroll
      for (int i = 0; i < 4; ++i)
        a[i] = *(const short8*)&lA[(wm + i * 16 + lr) * 72 + kk * 32 + quad * 8];
#pragma unroll
      for (int j = 0; j < 4; ++j)
        b[j] = *(const short8*)&lB[(wn + j * 16 + lr) * 72 + kk * 32 + quad * 8];
#pragma unroll
      for (int i = 0; i < 4; ++i)
#pragma unroll
        for (int j = 0; j < 4; ++j)
          acc[i][j] = __builtin_amdgcn_mfma_f32_16x16x32_bf16(a[i], b[j], acc[i][j], 0, 0, 0);
    }
  }

  if (mode == 0) {
    const int which = n0 >> 10;  // block-uniform: 0=q 1=k 2=v
    const float* bias = (which == 0) ? bq : (which == 1) ? bk : bv;
#pragma unroll
    for (int i = 0; i < 4; ++i)
#pragma unroll
      for (int j = 0; j < 4; ++j)
#pragma unroll
        for (int r = 0; r < 4; ++r) {
          const int row = m0 + wm + i * 16 + quad * 4 + r;
          const int col = n0 + wn + j * 16 + lr;
          const int c = col & 1023;
          float val = acc[i][j][r] + bias[c];
          const int head = c >> 6, hd_i = c & 63;
          const int b_ = row >> 11, pos = row & 2047;
          if (which < 2) {  // RoPE: pair partner is adjacent column = adjacent lane
            const float partner = __shfl_xor(val, 1);
            const int ip = hd_i >> 1;
            const float invf = exp2f((float)ip * -0.41524100988676073f);  // 10000^(-2i/64)
            const float fr = (float)pos * invf;
            float sn, cs;
            __sincosf(fr, &sn, &cs);
            val = fmaf(partner, (lane & 1) ? sn : -sn, val * cs);
          }
          if (which == 2) {
            vtb[((size_t)((b_ * 16 + head) * 64 + hd_i)) * SEQ + pos] = f2bf(val);
          } else {
            const size_t didx = ((size_t)((b_ * 16 + head) * SEQ + pos)) * 64 + hd_i;
            if (which == 0) qb[didx] = f2bf(val);
            else            kb[didx] = f2bf(val);
          }
        }
  } else {
#pragma unroll
    for (int i = 0; i < 4; ++i)
#pragma unroll
      for (int j = 0; j < 4; ++j)
#pragma unroll
        for (int r = 0; r < 4; ++r) {
          const int row = m0 + wm + i * 16 + quad * 4 + r;
          const int col = n0 + wn + j * 16 + lr;
          const size_t idx = (size_t)row * 1024 + col;
          out[idx] = acc[i][j][r] + bo[col] + xres[idx];
        }
  }
}

// ---------------- flash attention (non-causal), 64 q-rows/block, 64-key tiles ----------------
__global__ __launch_bounds__(256) void attn_kernel(
    const unsigned short* __restrict__ qg, const unsigned short* __restrict__ kg,
    const unsigned short* __restrict__ vtg, unsigned short* __restrict__ ao) {
  __shared__ unsigned short lK[64 * 72];      // 64 keys x 64 d
  __shared__ unsigned short lV[64 * 72];      // transposed: 64 d x 64 keys
  __shared__ unsigned short lP[4][16 * 72];   // per-wave P round-trip
  const int tid = threadIdx.x;
  const int lane = tid & 63, wave = tid >> 6;
  const int lr = lane & 15, quad = lane >> 4;
  const int bh = blockIdx.x >> 5, qt = blockIdx.x & 31;
  const int q0 = qt * 64 + wave * 16;
  const unsigned short* Q  = qg + (size_t)bh * SEQ * 64;
  const unsigned short* K  = kg + (size_t)bh * SEQ * 64;
  const unsigned short* VT = vtg + (size_t)bh * 64 * SEQ;

  short8 qf[2];
#pragma unroll
  for (int kk = 0; kk < 2; ++kk)
    qf[kk] = *(const short8*)&Q[(size_t)(q0 + lr) * 64 + kk * 32 + quad * 8];

  float m_run[4], l_run[4];
  f32x4 o[4];
#pragma unroll
  for (int r = 0; r < 4; ++r) { m_run[r] = -1e30f; l_run[r] = 0.0f; }
#pragma unroll
  for (int d = 0; d < 4; ++d) o[d] = (f32x4){0.f, 0.f, 0.f, 0.f};

  for (int kt = 0; kt < 32; ++kt) {
    __syncthreads();  // protect previous iteration's LDS reads
#pragma unroll
    for (int p = 0; p < 2; ++p) {
      int u = tid + p * 256;
      int row = u >> 3, c16 = u & 7;
      *(uint4*)&lK[row * 72 + c16 * 8] =
          *(const uint4*)&K[(size_t)(kt * 64 + row) * 64 + c16 * 8];
      *(uint4*)&lV[row * 72 + c16 * 8] =
          *(const uint4*)&VT[(size_t)row * SEQ + kt * 64 + c16 * 8];
    }
    __syncthreads();

    f32x4 s[4];
#pragma unroll
    for (int kb2 = 0; kb2 < 4; ++kb2) {
      f32x4 accs = (f32x4){0.f, 0.f, 0.f, 0.f};
#pragma unroll
      for (int kk = 0; kk < 2; ++kk) {
        short8 kf = *(const short8*)&lK[(kb2 * 16 + lr) * 72 + kk * 32 + quad * 8];
        accs = __builtin_amdgcn_mfma_f32_16x16x32_bf16(qf[kk], kf, accs, 0, 0, 0);
      }
      s[kb2] = accs * 0.125f;  // 1/sqrt(64)
    }

    // online softmax: lane holds rows quad*4+r, cols lane&15 (per key-block)
#pragma unroll
    for (int r = 0; r < 4; ++r) {
      float mx = fmaxf(fmaxf(s[0][r], s[1][r]), fmaxf(s[2][r], s[3][r]));
#pragma unroll
      for (int off = 1; off <= 8; off <<= 1) mx = fmaxf(mx, __shfl_xor(mx, off));
      mx = fmaxf(mx, m_run[r]);
      const float alpha = __expf(m_run[r] - mx);
      m_run[r] = mx;
      float rs = 0.0f;
#pragma unroll
      for (int kb2 = 0; kb2 < 4; ++kb2) {
        float p = __expf(s[kb2][r] - mx);
        s[kb2][r] = p;
        rs += p;
      }
#pragma unroll
      for (int off = 1; off <= 8; off <<= 1) rs += __shfl_xor(rs, off);
      l_run[r] = l_run[r] * alpha + rs;
#pragma unroll
      for (int d = 0; d < 4; ++d) o[d][r] *= alpha;
    }

    // P: C-layout -> LDS -> A-layout
#pragma unroll
    for (int kb2 = 0; kb2 < 4; ++kb2)
#pragma unroll
      for (int r = 0; r < 4; ++r)
        lP[wave][(quad * 4 + r) * 72 + kb2 * 16 + lr] = f2bf(s[kb2][r]);
    __syncthreads();

#pragma unroll
    for (int k2 = 0; k2 < 2; ++k2) {
      short8 pf = *(const short8*)&lP[wave][lr * 72 + k2 * 32 + quad * 8];
#pragma unroll
      for (int d = 0; d < 4; ++d) {
        short8 vf = *(const short8*)&lV[(d * 16 + lr) * 72 + k2 * 32 + quad * 8];
        o[d] = __builtin_amdgcn_mfma_f32_16x16x32_bf16(pf, vf, o[d], 0, 0, 0);
      }
    }
  }

  const int b_ = bh >> 4, h = bh & 15;
#pragma unroll
  for (int d = 0; d < 4; ++d)
#pragma unroll
    for (int r = 0; r < 4; ++r) {
      const int row = q0 + quad * 4 + r;
      const size_t idx = (size_t)(b_ * SEQ + row) * 1024 + h * 64 + d * 16 + lr;
      ao[idx] = f2bf(o[d][r] / l_run[r]);
    }
}

// ---------------- launch ----------------
extern "C" void kernel_launch(void* const* d_in, const int* in_sizes, int n_in,
                              void* d_out, int out_size, void* d_ws, size_t ws_size,
                              hipStream_t stream) {
  const float* x   = (const float*)d_in[0];
  const float* lnw = (const float*)d_in[1];
  const float* lnb = (const float*)d_in[2];
  const float* Wq  = (const float*)d_in[3];
  const float* bq  = (const float*)d_in[4];
  const float* Wk  = (const float*)d_in[5];
  const float* bk  = (const float*)d_in[6];
  const float* Wv  = (const float*)d_in[7];
  const float* bv  = (const float*)d_in[8];
  const float* Wo  = (const float*)d_in[9];
  const float* bo  = (const float*)d_in[10];
  float* out = (float*)d_out;

  char* ws = (char*)d_ws;
  unsigned short* wqkv = (unsigned short*)(ws);               //  6 MB: [3][1024][1024] bf16
  unsigned short* wob  = (unsigned short*)(ws + 6291456);     //  2 MB
  unsigned short* xn   = (unsigned short*)(ws + 8388608);     //  8 MB: 4096x1024 bf16
  unsigned short* qb   = (unsigned short*)(ws + 16777216);    //  8 MB: (B,H,N,hd)
  unsigned short* kbuf = (unsigned short*)(ws + 25165824);    //  8 MB: (B,H,N,hd)
  unsigned short* vtb  = (unsigned short*)(ws + 33554432);    //  8 MB: (B,H,hd,N)
  unsigned short* ao   = (unsigned short*)(ws + 41943040);    //  8 MB: (B,N,D)

  hipLaunchKernelGGL(convw_kernel, dim3(4096), dim3(256), 0, stream, Wq, Wk, Wv, Wo, wqkv, wob);
  hipLaunchKernelGGL(ln_kernel, dim3(4096), dim3(256), 0, stream, x, lnw, lnb, xn);
  hipLaunchKernelGGL(gemm_kernel, dim3(24, 32), dim3(256), 0, stream,
                     xn, wqkv, 0, bq, bk, bv, qb, kbuf, vtb,
                     (const float*)nullptr, (const float*)nullptr, (float*)nullptr);
  hipLaunchKernelGGL(attn_kernel, dim3(1024), dim3(256), 0, stream, qb, kbuf, vtb, ao);
  hipLaunchKernelGGL(gemm_kernel, dim3(8, 32), dim3(256), 0, stream,
                     ao, wob, 1,
                     (const float*)nullptr, (const float*)nullptr, (const float*)nullptr,
                     (unsigned short*)nullptr, (unsigned short*)nullptr, (unsigned short*)nullptr,
                     bo, x, out);
}

// Round 2
// 283.893 us; speedup vs baseline: 1.0831x; 1.0831x over previous
//
#include <hip/hip_runtime.h>

// BottleneckAttention: LN -> QKV(+bias) -> RoPE(q,k) -> softmax(QK^T/8)V -> O-proj + residual
// B=2 N=2048 D=1024 H=16 hd=64. bf16 MFMA 16x16x32, fp32 accum.
// Layouts (learn_hip m89/m91): C/D: col=lane&15, row=(lane>>4)*4+reg
//                              A/B: m(or n)=lane&15, k=(lane>>4)*8+j
// Attention v2: no-max base-2 softmax (q pre-scaled by 0.125*log2e), S computed
// transposed (A=K,B=Q) so P-pack is ds_write_b64, row-sum l via ones-frag MFMA.

#define SEQ 2048
#define LN_EPS 1e-5f

using short8 = __attribute__((ext_vector_type(8))) short;
using f32x4  = __attribute__((ext_vector_type(4))) float;

__device__ __forceinline__ unsigned short f2bf(float f) {
  union { float f; unsigned u; } v; v.f = f;
  unsigned r = v.u + 0x7FFFu + ((v.u >> 16) & 1u);  // RNE
  return (unsigned short)(r >> 16);
}

__device__ __forceinline__ void async16(const void* g, void* l) {
  __builtin_amdgcn_global_load_lds(
      (const __attribute__((address_space(1))) void*)g,
      (__attribute__((address_space(3))) void*)l, 16, 0, 0);
}

// ---------------- weight fp32 -> bf16 ----------------
__global__ __launch_bounds__(256) void convw_kernel(
    const float* __restrict__ wq, const float* __restrict__ wk,
    const float* __restrict__ wv, const float* __restrict__ wo,
    unsigned short* __restrict__ wqkv, unsigned short* __restrict__ wob) {
  const int gid = blockIdx.x * 256 + threadIdx.x;   // 1M float4 units total
  const int m = gid >> 18, e4 = gid & 262143;
  const float* src = (m == 0) ? wq : (m == 1) ? wk : (m == 2) ? wv : wo;
  const float4 v = ((const float4*)src)[e4];
  ushort4 o; o.x = f2bf(v.x); o.y = f2bf(v.y); o.z = f2bf(v.z); o.w = f2bf(v.w);
  if (m < 3) ((ushort4*)wqkv)[(size_t)m * 262144 + e4] = o;
  else       ((ushort4*)wob)[e4] = o;
}

// ---------------- RoPE cos/sin table: tab[pos][i] = (cos, sin) ----------------
__global__ __launch_bounds__(256) void rope_tab_kernel(float2* __restrict__ tab) {
  const int gid = blockIdx.x * 256 + threadIdx.x;  // 65536 = 2048*32
  const int pos = gid >> 5, ip = gid & 31;
  const float invf = exp2f((float)ip * -0.4152410118609203f);  // 10000^(-2i/64)
  const float fr = (float)pos * invf;
  tab[gid] = make_float2(cosf(fr), sinf(fr));
}

// ---------------- layernorm -> bf16 ----------------
__global__ __launch_bounds__(256) void ln_kernel(
    const float* __restrict__ x, const float* __restrict__ w,
    const float* __restrict__ b, unsigned short* __restrict__ xn) {
  const int row = blockIdx.x, t = threadIdx.x;
  const float4 v = ((const float4*)(x + (size_t)row * 1024))[t];
  float s  = v.x + v.y + v.z + v.w;
  float s2 = v.x * v.x + v.y * v.y + v.z * v.z + v.w * v.w;
#pragma unroll
  for (int off = 32; off >= 1; off >>= 1) {
    s  += __shfl_xor(s, off);
    s2 += __shfl_xor(s2, off);
  }
  __shared__ float red[8];
  const int lane = t & 63, wave = t >> 6;
  if (lane == 0) { red[wave] = s; red[4 + wave] = s2; }
  __syncthreads();
  s  = red[0] + red[1] + red[2] + red[3];
  s2 = red[4] + red[5] + red[6] + red[7];
  const float mu   = s * (1.0f / 1024.0f);
  const float var  = s2 * (1.0f / 1024.0f) - mu * mu;
  const float rstd = rsqrtf(var + LN_EPS);
  const float4 wv = ((const float4*)w)[t];
  const float4 bv = ((const float4*)b)[t];
  ushort4 o;
  o.x = f2bf((v.x - mu) * rstd * wv.x + bv.x);
  o.y = f2bf((v.y - mu) * rstd * wv.y + bv.y);
  o.z = f2bf((v.z - mu) * rstd * wv.z + bv.z);
  o.w = f2bf((v.w - mu) * rstd * wv.w + bv.w);
  ((ushort4*)xn)[(size_t)row * 256 + t] = o;
}

// ---------------- 128x128 MFMA GEMM, C = A * Bw^T (+epilogue) ----------------
// mode 0: QKV  -> bias (+0.18*q scale) + RoPE(q,k), write q,k (B,H,N,hd), v^T (B,H,hd,N)
// mode 1: Oproj-> + bo + residual x, fp32 out
__global__ __launch_bounds__(256) void gemm_kernel(
    const unsigned short* __restrict__ A,   // M x 1024 bf16, row-major
    const unsigned short* __restrict__ Bw,  // Ncols x 1024 bf16 (one row per output col)
    int mode,
    const float* __restrict__ bq, const float* __restrict__ bk, const float* __restrict__ bv,
    const float2* __restrict__ tab,
    unsigned short* __restrict__ qb, unsigned short* __restrict__ kbg,
    unsigned short* __restrict__ vtb,
    const float* __restrict__ bo, const float* __restrict__ xres, float* __restrict__ out) {
  __shared__ unsigned short lA[128 * 64];
  __shared__ unsigned short lB[128 * 64];
  const int tid = threadIdx.x;
  const int lane = tid & 63, wave = tid >> 6;
  const int lr = lane & 15, quad = lane >> 4;
  const int wm = (wave >> 1) * 64, wn = (wave & 1) * 64;
  const int n0 = blockIdx.x * 128, m0 = blockIdx.y * 128;

  f32x4 acc[4][4];
#pragma unroll
  for (int i = 0; i < 4; ++i)
#pragma unroll
    for (int j = 0; j < 4; ++j) acc[i][j] = (f32x4){0.f, 0.f, 0.f, 0.f};

  for (int kt = 0; kt < 16; ++kt) {
    __syncthreads();
#pragma unroll
    for (int c = 0; c < 4; ++c) {
      const int chunk = wave * 4 + c;               // 0..15: 1KB chunks (8 rows)
      const int grow = chunk * 8 + (lane >> 3);
      const int gcol = (lane & 7) * 8;
      async16(&A[(size_t)(m0 + grow) * 1024 + kt * 64 + gcol], &lA[chunk * 512]);
      async16(&Bw[(size_t)(n0 + grow) * 1024 + kt * 64 + gcol], &lB[chunk * 512]);
    }
    __syncthreads();
#pragma unroll
    for (int kk = 0; kk < 2; ++kk) {
      short8 a[4], b[4];
#pragma unroll
      for (int i = 0; i < 4; ++i)
        a[i] = *(const short8*)&lA[(wm + i * 16 + lr) * 64 + kk * 32 + quad * 8];
#pragma unroll
      for (int j = 0; j < 4; ++j)
        b[j] = *(const short8*)&lB[(wn + j * 16 + lr) * 64 + kk * 32 + quad * 8];
#pragma unroll
      for (int i = 0; i < 4; ++i)
#pragma unroll
        for (int j = 0; j < 4; ++j)
          acc[i][j] = __builtin_amdgcn_mfma_f32_16x16x32_bf16(a[i], b[j], acc[i][j], 0, 0, 0);
    }
  }

  if (mode == 0) {
    const int which = n0 >> 10;  // block-uniform: 0=q 1=k 2=v
    const float* bias = (which == 0) ? bq : (which == 1) ? bk : bv;
    const float qs = (which == 0) ? 0.18033688011112042f : 1.0f;  // 0.125*log2(e)
#pragma unroll
    for (int i = 0; i < 4; ++i)
#pragma unroll
      for (int j = 0; j < 4; ++j)
#pragma unroll
        for (int r = 0; r < 4; ++r) {
          const int row = m0 + wm + i * 16 + quad * 4 + r;
          const int col = n0 + wn + j * 16 + lr;
          const int c = col & 1023;
          float val = (acc[i][j][r] + bias[c]) * qs;
          const int head = c >> 6, hd_i = c & 63;
          const int b_ = row >> 11, pos = row & 2047;
          if (which < 2) {  // RoPE: pair partner is adjacent column = adjacent lane
            const float partner = __shfl_xor(val, 1);
            const float2 cs = tab[(pos << 5) + (hd_i >> 1)];
            val = val * cs.x + partner * ((lane & 1) ? cs.y : -cs.y);
          }
          if (which == 2) {
            vtb[((size_t)((b_ * 16 + head) * 64 + hd_i)) * SEQ + pos] = f2bf(val);
          } else {
            const size_t didx = ((size_t)((b_ * 16 + head) * SEQ + pos)) * 64 + hd_i;
            if (which == 0) qb[didx] = f2bf(val);
            else            kbg[didx] = f2bf(val);
          }
        }
  } else {
#pragma unroll
    for (int i = 0; i < 4; ++i)
#pragma unroll
      for (int j = 0; j < 4; ++j)
#pragma unroll
        for (int r = 0; r < 4; ++r) {
          const int row = m0 + wm + i * 16 + quad * 4 + r;
          const int col = n0 + wn + j * 16 + lr;
          const size_t idx = (size_t)row * 1024 + col;
          out[idx] = acc[i][j][r] + bo[col] + xres[idx];
        }
  }
}

// ---------------- attention v2: 128 q-rows/block (4 waves x 32), 64-key tiles ----------------
__global__ __launch_bounds__(256) void attn_kernel(
    const unsigned short* __restrict__ qg, const unsigned short* __restrict__ kg,
    const unsigned short* __restrict__ vtg, unsigned short* __restrict__ ao) {
  __shared__ unsigned short lK[64 * 72];     // 64 keys x 64 d (+pad)
  __shared__ unsigned short lV[64 * 72];     // V^T: 64 d x 64 keys (+pad)
  __shared__ unsigned short lP[128 * 72];    // P: 128 q-rows x 64 keys (+pad), per-wave 32-row slice
  const int tid = threadIdx.x;
  const int lane = tid & 63, w = tid >> 6;
  const int lr = lane & 15, quad = lane >> 4;
  const int bh = blockIdx.x >> 4, qt = blockIdx.x & 15;
  const int q0 = qt * 128 + w * 32;
  const unsigned short* Q  = qg + (size_t)bh * SEQ * 64;
  const unsigned short* K  = kg + (size_t)bh * SEQ * 64;
  const unsigned short* VT = vtg + (size_t)bh * 64 * SEQ;

  short8 qf[2][2];
#pragma unroll
  for (int t = 0; t < 2; ++t)
#pragma unroll
    for (int kk = 0; kk < 2; ++kk)
      qf[t][kk] = *(const short8*)&Q[(size_t)(q0 + t * 16 + lr) * 64 + kk * 32 + quad * 8];

  short8 onesf;  // B-frag of e0 column: B[0][k]=1 -> row-sum lands in col 0
  {
    const short o1 = (lr == 0) ? (short)0x3F80 : (short)0;
#pragma unroll
    for (int j = 0; j < 8; ++j) onesf[j] = o1;
  }

  f32x4 o[2][4], ol[2];
#pragma unroll
  for (int t = 0; t < 2; ++t) {
    ol[t] = (f32x4){0.f, 0.f, 0.f, 0.f};
#pragma unroll
    for (int d = 0; d < 4; ++d) o[t][d] = (f32x4){0.f, 0.f, 0.f, 0.f};
  }

  for (int kt = 0; kt < 32; ++kt) {
    __syncthreads();
#pragma unroll
    for (int p = 0; p < 2; ++p) {
      const int idx = p * 256 + tid;               // 512 granule-writes
      const int row = idx >> 3, g = idx & 7;
      *(uint4*)&lK[row * 72 + g * 8] = *(const uint4*)&K[(size_t)(kt * 64 + row) * 64 + g * 8];
      *(uint4*)&lV[row * 72 + g * 8] = *(const uint4*)&VT[(size_t)row * SEQ + kt * 64 + g * 8];
    }
    __syncthreads();

    // S^T = K . Q^T : C rows = keys (quad*4+r), cols = q (lr). q pre-scaled by 0.125*log2e.
#pragma unroll
    for (int kb = 0; kb < 4; ++kb) {
      const short8 k0 = *(const short8*)&lK[(kb * 16 + lr) * 72 + quad * 8];
      const short8 k1 = *(const short8*)&lK[(kb * 16 + lr) * 72 + 32 + quad * 8];
#pragma unroll
      for (int t = 0; t < 2; ++t) {
        f32x4 st = (f32x4){0.f, 0.f, 0.f, 0.f};
        st = __builtin_amdgcn_mfma_f32_16x16x32_bf16(k0, qf[t][0], st, 0, 0, 0);
        st = __builtin_amdgcn_mfma_f32_16x16x32_bf16(k1, qf[t][1], st, 0, 0, 0);
        // p = 2^st  (no max subtraction: scores are O(1), fp32 range is ample)
        union { float f; unsigned u; } c0, c1, c2, c3;
        c0.f = __builtin_amdgcn_exp2f(st[0]);
        c1.f = __builtin_amdgcn_exp2f(st[1]);
        c2.f = __builtin_amdgcn_exp2f(st[2]);
        c3.f = __builtin_amdgcn_exp2f(st[3]);
        // pack 4 bf16 (truncate; l sums the same truncated values, so norm cancels)
        uint2 pw;
        pw.x = __builtin_amdgcn_perm(c1.u, c0.u, 0x07060302u);
        pw.y = __builtin_amdgcn_perm(c3.u, c2.u, 0x07060302u);
        // P[q = w*32+t*16+lr][keys kb*16+quad*4 .. +3]
        *(uint2*)&lP[(w * 32 + t * 16 + lr) * 72 + kb * 16 + quad * 4] = pw;
      }
    }
    __asm__ __volatile__("s_waitcnt lgkmcnt(0)" ::: "memory");

    // PV + row-sum l (ones-frag). pf is A-frag of P (per-wave slice, no barrier needed).
#pragma unroll
    for (int k2 = 0; k2 < 2; ++k2) {
      const short8 pf0 = *(const short8*)&lP[(w * 32 + lr) * 72 + k2 * 32 + quad * 8];
      const short8 pf1 = *(const short8*)&lP[(w * 32 + 16 + lr) * 72 + k2 * 32 + quad * 8];
      ol[0] = __builtin_amdgcn_mfma_f32_16x16x32_bf16(pf0, onesf, ol[0], 0, 0, 0);
      ol[1] = __builtin_amdgcn_mfma_f32_16x16x32_bf16(pf1, onesf, ol[1], 0, 0, 0);
#pragma unroll
      for (int d = 0; d < 4; ++d) {
        const short8 vf = *(const short8*)&lV[(d * 16 + lr) * 72 + k2 * 32 + quad * 8];
        o[0][d] = __builtin_amdgcn_mfma_f32_16x16x32_bf16(pf0, vf, o[0][d], 0, 0, 0);
        o[1][d] = __builtin_amdgcn_mfma_f32_16x16x32_bf16(pf1, vf, o[1][d], 0, 0, 0);
      }
    }
  }

  const int b_ = bh >> 4, h = bh & 15;
#pragma unroll
  for (int t = 0; t < 2; ++t)
#pragma unroll
    for (int r = 0; r < 4; ++r) {
      const float l = __shfl(ol[t][r], lane & 48);   // broadcast from lr==0 of this quad
      const float rl = 1.0f / l;
#pragma unroll
      for (int d = 0; d < 4; ++d) {
        const int row = q0 + t * 16 + quad * 4 + r;
        ao[(size_t)(b_ * SEQ + row) * 1024 + h * 64 + d * 16 + lr] = f2bf(o[t][d][r] * rl);
      }
    }
}

// ---------------- launch ----------------
extern "C" void kernel_launch(void* const* d_in, const int* in_sizes, int n_in,
                              void* d_out, int out_size, void* d_ws, size_t ws_size,
                              hipStream_t stream) {
  const float* x   = (const float*)d_in[0];
  const float* lnw = (const float*)d_in[1];
  const float* lnb = (const float*)d_in[2];
  const float* Wq  = (const float*)d_in[3];
  const float* bq  = (const float*)d_in[4];
  const float* Wk  = (const float*)d_in[5];
  const float* bk  = (const float*)d_in[6];
  const float* Wv  = (const float*)d_in[7];
  const float* bv  = (const float*)d_in[8];
  const float* Wo  = (const float*)d_in[9];
  const float* bo  = (const float*)d_in[10];
  float* out = (float*)d_out;

  char* ws = (char*)d_ws;
  unsigned short* wqkv = (unsigned short*)(ws);               //  6 MB: [3][1024][1024] bf16
  unsigned short* wob  = (unsigned short*)(ws + 6291456);     //  2 MB
  unsigned short* xn   = (unsigned short*)(ws + 8388608);     //  8 MB: 4096x1024 bf16
  unsigned short* qb   = (unsigned short*)(ws + 16777216);    //  8 MB: (B,H,N,hd)
  unsigned short* kbuf = (unsigned short*)(ws + 25165824);    //  8 MB: (B,H,N,hd)
  unsigned short* vtb  = (unsigned short*)(ws + 33554432);    //  8 MB: (B,H,hd,N)
  unsigned short* ao   = (unsigned short*)(ws + 41943040);    //  8 MB: (B,N,D)
  float2*         tab  = (float2*)(ws + 41943040);            // 512KB, dead before attn writes ao

  hipLaunchKernelGGL(convw_kernel, dim3(4096), dim3(256), 0, stream, Wq, Wk, Wv, Wo, wqkv, wob);
  hipLaunchKernelGGL(rope_tab_kernel, dim3(256), dim3(256), 0, stream, tab);
  hipLaunchKernelGGL(ln_kernel, dim3(4096), dim3(256), 0, stream, x, lnw, lnb, xn);
  hipLaunchKernelGGL(gemm_kernel, dim3(24, 32), dim3(256), 0, stream,
                     xn, wqkv, 0, bq, bk, bv, tab, qb, kbuf, vtb,
                     (const float*)nullptr, (const float*)nullptr, (float*)nullptr);
  hipLaunchKernelGGL(attn_kernel, dim3(512), dim3(256), 0, stream, qb, kbuf, vtb, ao);
  hipLaunchKernelGGL(gemm_kernel, dim3(8, 32), dim3(256), 0, stream,
                     ao, wob, 1,
                     (const float*)nullptr, (const float*)nullptr, (const float*)nullptr, tab,
                     (unsigned short*)nullptr, (unsigned short*)nullptr, (unsigned short*)nullptr,
                     bo, x, out);
}

// Round 3
// 252.574 us; speedup vs baseline: 1.2174x; 1.1240x over previous
//
#include <hip/hip_runtime.h>

// BottleneckAttention: LN -> QKV(+bias) -> RoPE(q,k) -> softmax(QK^T/8)V -> O-proj + residual
// B=2 N=2048 D=1024 H=16 hd=64. bf16 MFMA 16x16x32, fp32 accum.
// Layouts (learn_hip m89/m91): C/D: col=lane&15, row=(lane>>4)*4+reg
//                              A/B: m(or n)=lane&15, k=(lane>>4)*8+j
// v3: LDS XOR swizzle (logical group g of row r at physical g^(r&7)) so
// global_load_lds (linear dest) coexists with conflict-free ds_read_b128.

#define SEQ 2048
#define LN_EPS 1e-5f

using short8 = __attribute__((ext_vector_type(8))) short;
using f32x4  = __attribute__((ext_vector_type(4))) float;

__device__ __forceinline__ unsigned short f2bf(float f) {
  union { float f; unsigned u; } v; v.f = f;
  unsigned r = v.u + 0x7FFFu + ((v.u >> 16) & 1u);  // RNE
  return (unsigned short)(r >> 16);
}

__device__ __forceinline__ void async16(const void* g, void* l) {
  __builtin_amdgcn_global_load_lds(
      (const __attribute__((address_space(1))) void*)g,
      (__attribute__((address_space(3))) void*)l, 16, 0, 0);
}

// ---------------- weight fp32 -> bf16 ----------------
__global__ __launch_bounds__(256) void convw_kernel(
    const float* __restrict__ wq, const float* __restrict__ wk,
    const float* __restrict__ wv, const float* __restrict__ wo,
    unsigned short* __restrict__ wqkv, unsigned short* __restrict__ wob) {
  const int gid = blockIdx.x * 256 + threadIdx.x;   // 1M float4 units total
  const int m = gid >> 18, e4 = gid & 262143;
  const float* src = (m == 0) ? wq : (m == 1) ? wk : (m == 2) ? wv : wo;
  const float4 v = ((const float4*)src)[e4];
  ushort4 o; o.x = f2bf(v.x); o.y = f2bf(v.y); o.z = f2bf(v.z); o.w = f2bf(v.w);
  if (m < 3) ((ushort4*)wqkv)[(size_t)m * 262144 + e4] = o;
  else       ((ushort4*)wob)[e4] = o;
}

// ---------------- RoPE cos/sin table: tab[pos][i] = (cos, sin) ----------------
__global__ __launch_bounds__(256) void rope_tab_kernel(float2* __restrict__ tab) {
  const int gid = blockIdx.x * 256 + threadIdx.x;  // 65536 = 2048*32
  const int pos = gid >> 5, ip = gid & 31;
  const float invf = exp2f((float)ip * -0.4152410118609203f);  // 10000^(-2i/64)
  const float fr = (float)pos * invf;
  tab[gid] = make_float2(cosf(fr), sinf(fr));
}

// ---------------- layernorm -> bf16 ----------------
__global__ __launch_bounds__(256) void ln_kernel(
    const float* __restrict__ x, const float* __restrict__ w,
    const float* __restrict__ b, unsigned short* __restrict__ xn) {
  const int row = blockIdx.x, t = threadIdx.x;
  const float4 v = ((const float4*)(x + (size_t)row * 1024))[t];
  float s  = v.x + v.y + v.z + v.w;
  float s2 = v.x * v.x + v.y * v.y + v.z * v.z + v.w * v.w;
#pragma unroll
  for (int off = 32; off >= 1; off >>= 1) {
    s  += __shfl_xor(s, off);
    s2 += __shfl_xor(s2, off);
  }
  __shared__ float red[8];
  const int lane = t & 63, wave = t >> 6;
  if (lane == 0) { red[wave] = s; red[4 + wave] = s2; }
  __syncthreads();
  s  = red[0] + red[1] + red[2] + red[3];
  s2 = red[4] + red[5] + red[6] + red[7];
  const float mu   = s * (1.0f / 1024.0f);
  const float var  = s2 * (1.0f / 1024.0f) - mu * mu;
  const float rstd = rsqrtf(var + LN_EPS);
  const float4 wv = ((const float4*)w)[t];
  const float4 bv = ((const float4*)b)[t];
  ushort4 o;
  o.x = f2bf((v.x - mu) * rstd * wv.x + bv.x);
  o.y = f2bf((v.y - mu) * rstd * wv.y + bv.y);
  o.z = f2bf((v.z - mu) * rstd * wv.z + bv.z);
  o.w = f2bf((v.w - mu) * rstd * wv.w + bv.w);
  ((ushort4*)xn)[(size_t)row * 256 + t] = o;
}

// ---------------- 128x128 MFMA GEMM, C = A * Bw^T (+epilogue) ----------------
// LDS swizzle: logical 16B-group g of row r stored at physical g^(r&7).
// mode 0: QKV  -> bias (+0.18*q scale) + RoPE(q,k), write q,k (B,H,N,hd), v^T (B,H,hd,N)
// mode 1: Oproj-> + bo + residual x, fp32 out
__global__ __launch_bounds__(256) void gemm_kernel(
    const unsigned short* __restrict__ A,   // M x 1024 bf16, row-major
    const unsigned short* __restrict__ Bw,  // Ncols x 1024 bf16 (one row per output col)
    int mode,
    const float* __restrict__ bq, const float* __restrict__ bk, const float* __restrict__ bv,
    const float2* __restrict__ tab,
    unsigned short* __restrict__ qb, unsigned short* __restrict__ kbg,
    unsigned short* __restrict__ vtb,
    const float* __restrict__ bo, const float* __restrict__ xres, float* __restrict__ out) {
  __shared__ unsigned short lA[128 * 64];
  __shared__ unsigned short lB[128 * 64];
  const int tid = threadIdx.x;
  const int lane = tid & 63, wave = tid >> 6;
  const int lr = lane & 15, quad = lane >> 4;
  const int wm = (wave >> 1) * 64, wn = (wave & 1) * 64;
  const int n0 = blockIdx.x * 128, m0 = blockIdx.y * 128;
  const int r7 = lr & 7;                      // read-side swizzle key
  const int lrow = lane >> 3, lcg = (lane & 7) ^ lrow;  // write-side: row-in-chunk, swizzled col-group

  f32x4 acc[4][4];
#pragma unroll
  for (int i = 0; i < 4; ++i)
#pragma unroll
    for (int j = 0; j < 4; ++j) acc[i][j] = (f32x4){0.f, 0.f, 0.f, 0.f};

  for (int kt = 0; kt < 16; ++kt) {
    __syncthreads();
#pragma unroll
    for (int c = 0; c < 4; ++c) {
      const int chunk = wave * 4 + c;               // 0..15: 1KB chunks (8 rows)
      const int grow = chunk * 8 + lrow;
      async16(&A[(size_t)(m0 + grow) * 1024 + kt * 64 + lcg * 8], &lA[chunk * 512]);
      async16(&Bw[(size_t)(n0 + grow) * 1024 + kt * 64 + lcg * 8], &lB[chunk * 512]);
    }
    __syncthreads();
#pragma unroll
    for (int kk = 0; kk < 2; ++kk) {
      short8 a[4], b[4];
#pragma unroll
      for (int i = 0; i < 4; ++i)
        a[i] = *(const short8*)&lA[(wm + i * 16 + lr) * 64 + ((kk * 4 + quad) ^ r7) * 8];
#pragma unroll
      for (int j = 0; j < 4; ++j)
        b[j] = *(const short8*)&lB[(wn + j * 16 + lr) * 64 + ((kk * 4 + quad) ^ r7) * 8];
#pragma unroll
      for (int i = 0; i < 4; ++i)
#pragma unroll
        for (int j = 0; j < 4; ++j)
          acc[i][j] = __builtin_amdgcn_mfma_f32_16x16x32_bf16(a[i], b[j], acc[i][j], 0, 0, 0);
    }
  }

  if (mode == 0) {
    const int which = n0 >> 10;  // block-uniform: 0=q 1=k 2=v
    const float* bias = (which == 0) ? bq : (which == 1) ? bk : bv;
    const float qs = (which == 0) ? 0.18033688011112042f : 1.0f;  // 0.125*log2(e)
#pragma unroll
    for (int i = 0; i < 4; ++i)
#pragma unroll
      for (int j = 0; j < 4; ++j)
#pragma unroll
        for (int r = 0; r < 4; ++r) {
          const int row = m0 + wm + i * 16 + quad * 4 + r;
          const int col = n0 + wn + j * 16 + lr;
          const int c = col & 1023;
          float val = (acc[i][j][r] + bias[c]) * qs;
          const int head = c >> 6, hd_i = c & 63;
          const int b_ = row >> 11, pos = row & 2047;
          if (which < 2) {  // RoPE: pair partner is adjacent column = adjacent lane
            const float partner = __shfl_xor(val, 1);
            const float2 cs = tab[(pos << 5) + (hd_i >> 1)];
            val = val * cs.x + partner * ((lane & 1) ? cs.y : -cs.y);
          }
          if (which == 2) {
            vtb[((size_t)((b_ * 16 + head) * 64 + hd_i)) * SEQ + pos] = f2bf(val);
          } else {
            const size_t didx = ((size_t)((b_ * 16 + head) * SEQ + pos)) * 64 + hd_i;
            if (which == 0) qb[didx] = f2bf(val);
            else            kbg[didx] = f2bf(val);
          }
        }
  } else {
#pragma unroll
    for (int i = 0; i < 4; ++i)
#pragma unroll
      for (int j = 0; j < 4; ++j)
#pragma unroll
        for (int r = 0; r < 4; ++r) {
          const int row = m0 + wm + i * 16 + quad * 4 + r;
          const int col = n0 + wn + j * 16 + lr;
          const size_t idx = (size_t)row * 1024 + col;
          out[idx] = acc[i][j][r] + bo[col] + xres[idx];
        }
  }
}

// ---------------- attention: 128 q-rows/block (4 waves x 32), 64-key tiles ----------------
// lK/lV linear + XOR swizzle (async staging); lP padded (plain ds ops).
__global__ __launch_bounds__(256) void attn_kernel(
    const unsigned short* __restrict__ qg, const unsigned short* __restrict__ kg,
    const unsigned short* __restrict__ vtg, unsigned short* __restrict__ ao) {
  __shared__ unsigned short lK[64 * 64];     // 64 keys x 64 d, swizzled
  __shared__ unsigned short lV[64 * 64];     // V^T: 64 d x 64 keys, swizzled
  __shared__ unsigned short lP[128 * 72];    // P: 128 q x 64 keys (+pad), per-wave 32-row slice
  const int tid = threadIdx.x;
  const int lane = tid & 63, w = tid >> 6;
  const int lr = lane & 15, quad = lane >> 4;
  const int r7 = lr & 7;
  const int lrow = lane >> 3, lcg = (lane & 7) ^ lrow;
  const int bh = blockIdx.x >> 4, qt = blockIdx.x & 15;
  const int q0 = qt * 128 + w * 32;
  const unsigned short* Q  = qg + (size_t)bh * SEQ * 64;
  const unsigned short* K  = kg + (size_t)bh * SEQ * 64;
  const unsigned short* VT = vtg + (size_t)bh * 64 * SEQ;

  short8 qf[2][2];
#pragma unroll
  for (int t = 0; t < 2; ++t)
#pragma unroll
    for (int kk = 0; kk < 2; ++kk)
      qf[t][kk] = *(const short8*)&Q[(size_t)(q0 + t * 16 + lr) * 64 + kk * 32 + quad * 8];

  short8 onesf;  // B-frag of e0 column: B[0][k]=1 -> row-sum lands in col 0
  {
    const short o1 = (lr == 0) ? (short)0x3F80 : (short)0;
#pragma unroll
    for (int j = 0; j < 8; ++j) onesf[j] = o1;
  }

  f32x4 o[2][4], ol[2];
#pragma unroll
  for (int t = 0; t < 2; ++t) {
    ol[t] = (f32x4){0.f, 0.f, 0.f, 0.f};
#pragma unroll
    for (int d = 0; d < 4; ++d) o[t][d] = (f32x4){0.f, 0.f, 0.f, 0.f};
  }

  for (int kt = 0; kt < 32; ++kt) {
    __syncthreads();
#pragma unroll
    for (int c = 0; c < 2; ++c) {
      const int chunk = w * 2 + c;               // 0..7: 1KB chunks (8 rows)
      const int row = chunk * 8 + lrow;
      async16(&K[(size_t)(kt * 64 + row) * 64 + lcg * 8], &lK[chunk * 512]);
      async16(&VT[(size_t)row * SEQ + kt * 64 + lcg * 8], &lV[chunk * 512]);
    }
    __syncthreads();

    // S^T = K . Q^T : C rows = keys (quad*4+r), cols = q (lr). q pre-scaled by 0.125*log2e.
#pragma unroll
    for (int kb = 0; kb < 4; ++kb) {
      const short8 k0 = *(const short8*)&lK[(kb * 16 + lr) * 64 + (quad ^ r7) * 8];
      const short8 k1 = *(const short8*)&lK[(kb * 16 + lr) * 64 + ((4 + quad) ^ r7) * 8];
#pragma unroll
      for (int t = 0; t < 2; ++t) {
        f32x4 st = (f32x4){0.f, 0.f, 0.f, 0.f};
        st = __builtin_amdgcn_mfma_f32_16x16x32_bf16(k0, qf[t][0], st, 0, 0, 0);
        st = __builtin_amdgcn_mfma_f32_16x16x32_bf16(k1, qf[t][1], st, 0, 0, 0);
        // p = 2^st  (no max subtraction: scores are O(1), fp32 range is ample)
        union { float f; unsigned u; } c0, c1, c2, c3;
        c0.f = __builtin_amdgcn_exp2f(st[0]);
        c1.f = __builtin_amdgcn_exp2f(st[1]);
        c2.f = __builtin_amdgcn_exp2f(st[2]);
        c3.f = __builtin_amdgcn_exp2f(st[3]);
        // pack 4 bf16 (truncate; l sums the same truncated values, so norm cancels)
        uint2 pw;
        pw.x = __builtin_amdgcn_perm(c1.u, c0.u, 0x07060302u);
        pw.y = __builtin_amdgcn_perm(c3.u, c2.u, 0x07060302u);
        // P[q = w*32+t*16+lr][keys kb*16+quad*4 .. +3]
        *(uint2*)&lP[(w * 32 + t * 16 + lr) * 72 + kb * 16 + quad * 4] = pw;
      }
    }
    __asm__ __volatile__("s_waitcnt lgkmcnt(0)" ::: "memory");

    // PV + row-sum l (ones-frag). pf is A-frag of P (per-wave slice, no barrier needed).
#pragma unroll
    for (int k2 = 0; k2 < 2; ++k2) {
      const short8 pf0 = *(const short8*)&lP[(w * 32 + lr) * 72 + k2 * 32 + quad * 8];
      const short8 pf1 = *(const short8*)&lP[(w * 32 + 16 + lr) * 72 + k2 * 32 + quad * 8];
      ol[0] = __builtin_amdgcn_mfma_f32_16x16x32_bf16(pf0, onesf, ol[0], 0, 0, 0);
      ol[1] = __builtin_amdgcn_mfma_f32_16x16x32_bf16(pf1, onesf, ol[1], 0, 0, 0);
#pragma unroll
      for (int d = 0; d < 4; ++d) {
        const short8 vf = *(const short8*)&lV[(d * 16 + lr) * 64 + ((k2 * 4 + quad) ^ r7) * 8];
        o[0][d] = __builtin_amdgcn_mfma_f32_16x16x32_bf16(pf0, vf, o[0][d], 0, 0, 0);
        o[1][d] = __builtin_amdgcn_mfma_f32_16x16x32_bf16(pf1, vf, o[1][d], 0, 0, 0);
      }
    }
  }

  const int b_ = bh >> 4, h = bh & 15;
#pragma unroll
  for (int t = 0; t < 2; ++t)
#pragma unroll
    for (int r = 0; r < 4; ++r) {
      const float l = __shfl(ol[t][r], lane & 48);   // broadcast from lr==0 of this quad
      const float rl = 1.0f / l;
#pragma unroll
      for (int d = 0; d < 4; ++d) {
        const int row = q0 + t * 16 + quad * 4 + r;
        ao[(size_t)(b_ * SEQ + row) * 1024 + h * 64 + d * 16 + lr] = f2bf(o[t][d][r] * rl);
      }
    }
}

// ---------------- launch ----------------
extern "C" void kernel_launch(void* const* d_in, const int* in_sizes, int n_in,
                              void* d_out, int out_size, void* d_ws, size_t ws_size,
                              hipStream_t stream) {
  const float* x   = (const float*)d_in[0];
  const float* lnw = (const float*)d_in[1];
  const float* lnb = (const float*)d_in[2];
  const float* Wq  = (const float*)d_in[3];
  const float* bq  = (const float*)d_in[4];
  const float* Wk  = (const float*)d_in[5];
  const float* bk  = (const float*)d_in[6];
  const float* Wv  = (const float*)d_in[7];
  const float* bv  = (const float*)d_in[8];
  const float* Wo  = (const float*)d_in[9];
  const float* bo  = (const float*)d_in[10];
  float* out = (float*)d_out;

  char* ws = (char*)d_ws;
  unsigned short* wqkv = (unsigned short*)(ws);               //  6 MB: [3][1024][1024] bf16
  unsigned short* wob  = (unsigned short*)(ws + 6291456);     //  2 MB
  unsigned short* xn   = (unsigned short*)(ws + 8388608);     //  8 MB: 4096x1024 bf16
  unsigned short* qb   = (unsigned short*)(ws + 16777216);    //  8 MB: (B,H,N,hd)
  unsigned short* kbuf = (unsigned short*)(ws + 25165824);    //  8 MB: (B,H,N,hd)
  unsigned short* vtb  = (unsigned short*)(ws + 33554432);    //  8 MB: (B,H,hd,N)
  unsigned short* ao   = (unsigned short*)(ws + 41943040);    //  8 MB: (B,N,D)
  float2*         tab  = (float2*)(ws + 50331648);            // 512KB

  hipLaunchKernelGGL(convw_kernel, dim3(4096), dim3(256), 0, stream, Wq, Wk, Wv, Wo, wqkv, wob);
  hipLaunchKernelGGL(rope_tab_kernel, dim3(256), dim3(256), 0, stream, tab);
  hipLaunchKernelGGL(ln_kernel, dim3(4096), dim3(256), 0, stream, x, lnw, lnb, xn);
  hipLaunchKernelGGL(gemm_kernel, dim3(24, 32), dim3(256), 0, stream,
                     xn, wqkv, 0, bq, bk, bv, tab, qb, kbuf, vtb,
                     (const float*)nullptr, (const float*)nullptr, (float*)nullptr);
  hipLaunchKernelGGL(attn_kernel, dim3(512), dim3(256), 0, stream, qb, kbuf, vtb, ao);
  hipLaunchKernelGGL(gemm_kernel, dim3(8, 32), dim3(256), 0, stream,
                     ao, wob, 1,
                     (const float*)nullptr, (const float*)nullptr, (const float*)nullptr, tab,
                     (unsigned short*)nullptr, (unsigned short*)nullptr, (unsigned short*)nullptr,
                     bo, x, out);
}